// Round 1
// baseline (2758.825 us; speedup 1.0000x reference)
//
#include <hip/hip_runtime.h>
#include <math.h>
#include <stdint.h>

#define B_ 2
#define S_ 2048
#define D_ 1024
#define H_ 8
#define HD_ 64
#define NT_ (B_*S_)   // 4096 tokens

static constexpr float LAMBDA_INIT = 0.47071301834358415f;
static constexpr float ONE_MINUS_LI = 1.0f - 0.47071301834358415f;

// ---------------------------------------------------------------- lam scalar
__global__ void lam_kernel(const float* __restrict__ lq1, const float* __restrict__ lk1,
                           const float* __restrict__ lq2, const float* __restrict__ lk2,
                           float* __restrict__ lam_out) {
    int t = threadIdx.x;  // 64 threads
    float p1 = lq1[t] * lk1[t];
    float p2 = lq2[t] * lk2[t];
    for (int off = 32; off; off >>= 1) {
        p1 += __shfl_xor(p1, off);
        p2 += __shfl_xor(p2, off);
    }
    if (t == 0) lam_out[0] = expf(p1) - expf(p2) + LAMBDA_INIT;
}

// ---------------------------------------------------------------- fp32 GEMM
// C[M,N] = A[M,K] @ B[K,N]  (+bias, +silu)   EPI: 0=none 1=bias 2=bias+silu
template <int EPI>
__global__ __launch_bounds__(256) void gemm_f32(const float* __restrict__ A,
                                                const float* __restrict__ Bm,
                                                const float* __restrict__ bias,
                                                float* __restrict__ C,
                                                int M, int N, int K) {
    __shared__ float As[64][17];   // [m][k], pad to break bank conflicts
    __shared__ float Bs[16][68];   // [k][n], pad 4 keeps float4-store alignment
    const int t  = threadIdx.x;
    const int tx = t & 15, ty = t >> 4;
    const int row0 = blockIdx.y * 64, col0 = blockIdx.x * 64;

    float acc[4][4] = {};

    const int ar = t >> 2, ak = (t & 3) * 4;   // A: 64 rows x 16 k
    const int bk = t >> 4, bc = (t & 15) * 4;  // B: 16 k x 64 cols
    const float* Aptr = A + (size_t)(row0 + ar) * K + ak;
    const float* Bptr = Bm + (size_t)bk * N + col0 + bc;

    for (int k0 = 0; k0 < K; k0 += 16) {
        float4 av = *(const float4*)(Aptr + k0);
        As[ar][ak + 0] = av.x; As[ar][ak + 1] = av.y;
        As[ar][ak + 2] = av.z; As[ar][ak + 3] = av.w;
        float4 bv = *(const float4*)(Bptr + (size_t)k0 * N);
        *(float4*)&Bs[bk][bc] = bv;
        __syncthreads();
#pragma unroll
        for (int kk = 0; kk < 16; ++kk) {
            float a_[4], b_[4];
#pragma unroll
            for (int i = 0; i < 4; ++i) a_[i] = As[ty * 4 + i][kk];
#pragma unroll
            for (int j = 0; j < 4; ++j) b_[j] = Bs[kk][tx * 4 + j];
#pragma unroll
            for (int i = 0; i < 4; ++i)
#pragma unroll
                for (int j = 0; j < 4; ++j) acc[i][j] += a_[i] * b_[j];
        }
        __syncthreads();
    }

#pragma unroll
    for (int i = 0; i < 4; ++i) {
        const int rr = row0 + ty * 4 + i;
#pragma unroll
        for (int j = 0; j < 4; ++j) {
            const int cc = col0 + tx * 4 + j;
            float v = acc[i][j];
            if (EPI >= 1) v += bias[cc];
            if (EPI == 2) v = v / (1.0f + expf(-v));   // silu
            C[(size_t)rr * N + cc] = v;
        }
    }
}

// ------------------------------------------------- RoPE + split + q2/k2 RMSNorm
// qkv: [4096][3072]. Writes q1,k1 (roped) and q2n,k2n (roped+sig+rmsnorm),
// each laid out [b][h][s][64].
__global__ __launch_bounds__(256) void rope_kernel(const float* __restrict__ qkv,
                                                   const float* __restrict__ sigmas,
                                                   const float* __restrict__ lnq_w,
                                                   const float* __restrict__ lnq_b,
                                                   float* __restrict__ q1, float* __restrict__ q2n,
                                                   float* __restrict__ k1, float* __restrict__ k2n) {
    const int tok = blockIdx.x;            // 0..4095
    const int b = tok / S_, s = tok % S_;
    const int t = threadIdx.x;
    const int hh = t >> 4;                 // 0..15 (head in 2H layout)
    const int l16 = t & 15;
    const int d0 = l16 * 4;

    const float* qrow = qkv + (size_t)tok * 3072 + hh * 64 + d0;
    float4 qv = *(const float4*)qrow;
    float4 kv = *(const float4*)(qrow + 1024);
    float q[4] = {qv.x, qv.y, qv.z, qv.w};
    float k[4] = {kv.x, kv.y, kv.z, kv.w};

    if (d0 < 32) {  // rotate first 32 dims, interleaved pairs
#pragma unroll
        for (int pr = 0; pr < 2; ++pr) {
            const int i = d0 / 2 + pr;     // freq index 0..15
            float freq = (float)s * powf(10000.0f, -(float)i / 16.0f);
            float sn, c;
            sincosf(freq, &sn, &c);
            float x0 = q[2 * pr], x1 = q[2 * pr + 1];
            q[2 * pr]     = x0 * c - x1 * sn;
            q[2 * pr + 1] = x1 * c + x0 * sn;
            x0 = k[2 * pr]; x1 = k[2 * pr + 1];
            k[2 * pr]     = x0 * c - x1 * sn;
            k[2 * pr + 1] = x1 * c + x0 * sn;
        }
    }

    const int h = hh >> 1, j = hh & 1;
    const size_t obase = ((size_t)(b * H_ + h) * S_ + s) * 64 + d0;
    if (j == 0) {
        *(float4*)&q1[obase] = make_float4(q[0], q[1], q[2], q[3]);
        *(float4*)&k1[obase] = make_float4(k[0], k[1], k[2], k[3]);
    } else {
        float ssq_q = 0.f, ssq_k = 0.f;
#pragma unroll
        for (int i = 0; i < 4; ++i) {
            const float sg = sigmas[b * 64 + d0 + i];
            q[i] += sg; k[i] += sg;
            ssq_q += q[i] * q[i];
            ssq_k += k[i] * k[i];
        }
        for (int off = 1; off < 16; off <<= 1) {
            ssq_q += __shfl_xor(ssq_q, off, 16);
            ssq_k += __shfl_xor(ssq_k, off, 16);
        }
        const float rq = rsqrtf(ssq_q / 64.0f + 1e-8f);
        const float rk = rsqrtf(ssq_k / 64.0f + 1e-8f);
        float oq[4], ok[4];
#pragma unroll
        for (int i = 0; i < 4; ++i) {
            const float w = lnq_w[d0 + i], bb = lnq_b[d0 + i];
            oq[i] = q[i] * rq * w + bb;
            ok[i] = k[i] * rk * w + bb;
        }
        *(float4*)&q2n[obase] = make_float4(oq[0], oq[1], oq[2], oq[3]);
        *(float4*)&k2n[obase] = make_float4(ok[0], ok[1], ok[2], ok[3]);
    }
}

// ------------------------------------------------- dual causal flash attention
// One block per (qtile=32 rows, h, b). Computes both attention branches sharing
// the V tile, then fuses attn1 - lam*attn2, per-head RMSNorm(128), *(1-LI).
// Output: a_rms [token][1024] row-major (head-major within row).
__global__ __launch_bounds__(256) void attn_kernel(const float* __restrict__ q1g,
                                                   const float* __restrict__ q2g,
                                                   const float* __restrict__ k1g,
                                                   const float* __restrict__ k2g,
                                                   const float* __restrict__ qkv,
                                                   const float* __restrict__ lamp,
                                                   const float* __restrict__ ln_w,
                                                   const float* __restrict__ ln_b,
                                                   float* __restrict__ out) {
    __shared__ float q1s[32][68], q2s[32][68];
    __shared__ float k1sT[64][33], k2sT[64][33];   // [d][key]
    __shared__ float vs[32][128];
    __shared__ float p1s[32][33], p2s[32][33];

    const int qt = blockIdx.x, h = blockIdx.y, b = blockIdx.z;
    const int q0 = qt * 32;
    const int t = threadIdx.x;
    const float lam = lamp[0];

    // load Q tiles (2048 elems each, 8 per thread)
    {
        const size_t qbase = ((size_t)(b * H_ + h) * S_ + q0) * 64;
        const int e = t * 8, r = e >> 6, c = e & 63;
        float4 a0 = *(const float4*)&q1g[qbase + e];
        float4 a1 = *(const float4*)&q1g[qbase + e + 4];
        *(float4*)&q1s[r][c] = a0; *(float4*)&q1s[r][c + 4] = a1;
        float4 b0 = *(const float4*)&q2g[qbase + e];
        float4 b1 = *(const float4*)&q2g[qbase + e + 4];
        *(float4*)&q2s[r][c] = b0; *(float4*)&q2s[r][c + 4] = b1;
    }

    const int r = t >> 3;        // query row in tile (0..31)
    const int cg = t & 7;        // col group (0..7)
    const int c0 = cg * 4;
    float m1 = -INFINITY, m2 = -INFINITY, l1 = 0.f, l2 = 0.f;
    float o1[16] = {}, o2[16] = {};

    for (int kt = 0; kt <= qt; ++kt) {
        const int k0 = kt * 32;
        __syncthreads();  // previous iter's LDS reads done
        // load K tiles transposed (scalar stores) + V tile
        {
            const size_t kbase = ((size_t)(b * H_ + h) * S_ + k0) * 64;
            const int e = t * 8, kr = e >> 6, kc = e & 63;
            float4 v0 = *(const float4*)&k1g[kbase + e];
            float4 v1 = *(const float4*)&k1g[kbase + e + 4];
            k1sT[kc + 0][kr] = v0.x; k1sT[kc + 1][kr] = v0.y;
            k1sT[kc + 2][kr] = v0.z; k1sT[kc + 3][kr] = v0.w;
            k1sT[kc + 4][kr] = v1.x; k1sT[kc + 5][kr] = v1.y;
            k1sT[kc + 6][kr] = v1.z; k1sT[kc + 7][kr] = v1.w;
            float4 w0 = *(const float4*)&k2g[kbase + e];
            float4 w1 = *(const float4*)&k2g[kbase + e + 4];
            k2sT[kc + 0][kr] = w0.x; k2sT[kc + 1][kr] = w0.y;
            k2sT[kc + 2][kr] = w0.z; k2sT[kc + 3][kr] = w0.w;
            k2sT[kc + 4][kr] = w1.x; k2sT[kc + 5][kr] = w1.y;
            k2sT[kc + 6][kr] = w1.z; k2sT[kc + 7][kr] = w1.w;
            const int vr = t >> 3, vc = (t & 7) * 16;
            const float* vp = qkv + ((size_t)(b * S_ + k0 + vr)) * 3072 + 2048 + h * 128 + vc;
            float4 x0 = *(const float4*)(vp + 0);
            float4 x1 = *(const float4*)(vp + 4);
            float4 x2 = *(const float4*)(vp + 8);
            float4 x3 = *(const float4*)(vp + 12);
            *(float4*)&vs[vr][vc + 0]  = x0;
            *(float4*)&vs[vr][vc + 4]  = x1;
            *(float4*)&vs[vr][vc + 8]  = x2;
            *(float4*)&vs[vr][vc + 12] = x3;
        }
        __syncthreads();

        // scores: 4 cols x 2 branches per thread
        float s1[4] = {}, s2[4] = {};
#pragma unroll 8
        for (int d = 0; d < 64; ++d) {
            const float a1 = q1s[r][d], a2 = q2s[r][d];
#pragma unroll
            for (int j = 0; j < 4; ++j) {
                s1[j] += a1 * k1sT[d][c0 + j];
                s2[j] += a2 * k2sT[d][c0 + j];
            }
        }
        const int qg = q0 + r;
        float mx1 = -INFINITY, mx2 = -INFINITY;
#pragma unroll
        for (int j = 0; j < 4; ++j) {
            const int kg = k0 + c0 + j;
            if (kg <= qg) { s1[j] *= 0.125f; s2[j] *= 0.125f; }
            else          { s1[j] = -INFINITY; s2[j] = -INFINITY; }
            mx1 = fmaxf(mx1, s1[j]); mx2 = fmaxf(mx2, s2[j]);
        }
        for (int off = 1; off < 8; off <<= 1) {
            mx1 = fmaxf(mx1, __shfl_xor(mx1, off, 8));
            mx2 = fmaxf(mx2, __shfl_xor(mx2, off, 8));
        }
        const float nm1 = fmaxf(m1, mx1), nm2 = fmaxf(m2, mx2);
        float p1[4], p2[4], sum1 = 0.f, sum2 = 0.f;
#pragma unroll
        for (int j = 0; j < 4; ++j) {
            p1[j] = expf(s1[j] - nm1); sum1 += p1[j];
            p2[j] = expf(s2[j] - nm2); sum2 += p2[j];
        }
        for (int off = 1; off < 8; off <<= 1) {
            sum1 += __shfl_xor(sum1, off, 8);
            sum2 += __shfl_xor(sum2, off, 8);
        }
        const float al1 = expf(m1 - nm1), al2 = expf(m2 - nm2);
        l1 = l1 * al1 + sum1; l2 = l2 * al2 + sum2;
        m1 = nm1; m2 = nm2;
#pragma unroll
        for (int dd = 0; dd < 16; ++dd) { o1[dd] *= al1; o2[dd] *= al2; }
#pragma unroll
        for (int j = 0; j < 4; ++j) { p1s[r][c0 + j] = p1[j]; p2s[r][c0 + j] = p2[j]; }
        __syncthreads();

        // PV: thread owns dims d = cg + 8*dd (dd=0..15)
#pragma unroll 4
        for (int c = 0; c < 32; ++c) {
            const float pp1 = p1s[r][c], pp2 = p2s[r][c];
#pragma unroll
            for (int dd = 0; dd < 16; ++dd) {
                const float vv = vs[c][cg + 8 * dd];
                o1[dd] += pp1 * vv;
                o2[dd] += pp2 * vv;
            }
        }
    }

    // epilogue: combine, RMSNorm over 128 dims, scale, store
    const float inv1 = 1.0f / l1, inv2 = 1.0f / l2;
    float comb[16]; float ss = 0.f;
#pragma unroll
    for (int dd = 0; dd < 16; ++dd) {
        const float cmb = o1[dd] * inv1 - lam * (o2[dd] * inv2);
        comb[dd] = cmb; ss += cmb * cmb;
    }
    for (int off = 1; off < 8; off <<= 1) ss += __shfl_xor(ss, off, 8);
    const float rms = rsqrtf(ss / 128.0f + 1e-8f);
    const size_t obase = ((size_t)(b * S_ + q0 + r)) * 1024 + h * 128;
#pragma unroll
    for (int dd = 0; dd < 16; ++dd) {
        const int d = cg + 8 * dd;
        out[obase + d] = (comb[dd] * rms * ln_w[d] + ln_b[d]) * ONE_MINUS_LI;
    }
}

// ---------------------------------------------------------------- add + LayerNorm
// out[row] = LN(X[row] + Y[row]) over 1024 dims
__global__ __launch_bounds__(256) void add_ln_kernel(const float* __restrict__ X,
                                                     const float* __restrict__ Y,
                                                     const float* __restrict__ w,
                                                     const float* __restrict__ bvec,
                                                     float* __restrict__ out, float eps) {
    const int row = blockIdx.x;
    const int t = threadIdx.x;
    __shared__ float red[4];

    float4 xv = *(const float4*)&X[(size_t)row * 1024 + t * 4];
    float4 yv = *(const float4*)&Y[(size_t)row * 1024 + t * 4];
    float v[4] = {xv.x + yv.x, xv.y + yv.y, xv.z + yv.z, xv.w + yv.w};

    float s = v[0] + v[1] + v[2] + v[3];
    for (int off = 1; off < 64; off <<= 1) s += __shfl_xor(s, off);
    if ((t & 63) == 0) red[t >> 6] = s;
    __syncthreads();
    const float mean = (red[0] + red[1] + red[2] + red[3]) * (1.0f / 1024.0f);

    float sq = 0.f;
#pragma unroll
    for (int i = 0; i < 4; ++i) { const float d = v[i] - mean; sq += d * d; }
    __syncthreads();   // red reuse
    for (int off = 1; off < 64; off <<= 1) sq += __shfl_xor(sq, off);
    if ((t & 63) == 0) red[t >> 6] = sq;
    __syncthreads();
    const float var = (red[0] + red[1] + red[2] + red[3]) * (1.0f / 1024.0f);
    const float rstd = rsqrtf(var + eps);

    float o[4];
#pragma unroll
    for (int i = 0; i < 4; ++i)
        o[i] = (v[i] - mean) * rstd * w[t * 4 + i] + bvec[t * 4 + i];
    *(float4*)&out[(size_t)row * 1024 + t * 4] = make_float4(o[0], o[1], o[2], o[3]);
}

// ---------------------------------------------------------------- launch
extern "C" void kernel_launch(void* const* d_in, const int* in_sizes, int n_in,
                              void* d_out, int out_size, void* d_ws, size_t ws_size,
                              hipStream_t stream) {
    const float* x      = (const float*)d_in[0];
    const float* sigmas = (const float*)d_in[1];
    const float* w_qkv  = (const float*)d_in[2];
    const float* w_out  = (const float*)d_in[3];
    const float* lq1    = (const float*)d_in[4];
    const float* lk1    = (const float*)d_in[5];
    const float* lq2    = (const float*)d_in[6];
    const float* lk2    = (const float*)d_in[7];
    const float* ln_w   = (const float*)d_in[8];
    const float* ln_b   = (const float*)d_in[9];
    const float* lnq_w  = (const float*)d_in[10];
    const float* lnq_b  = (const float*)d_in[11];
    const float* ln1_w  = (const float*)d_in[12];
    const float* ln1_b  = (const float*)d_in[13];
    const float* ln2_w  = (const float*)d_in[14];
    const float* ln2_b  = (const float*)d_in[15];
    const float* w1     = (const float*)d_in[16];
    const float* b1     = (const float*)d_in[17];
    const float* w2     = (const float*)d_in[18];
    const float* b2     = (const float*)d_in[19];

    float* ws = (float*)d_ws;
    // workspace layout (floats)
    const size_t OFF_QKV  = 0;                       // 4096*3072 = 12582912
    const size_t OFF_Q1   = 12582912;                // each 2*8*2048*64 = 2097152
    const size_t OFF_Q2   = OFF_Q1 + 2097152;
    const size_t OFF_K1   = OFF_Q2 + 2097152;
    const size_t OFF_K2   = OFF_K1 + 2097152;
    const size_t OFF_ARMS = OFF_K2 + 2097152;        // 4096*1024 = 4194304
    // reuse region (qkv + q/k buffers dead after attention)
    const size_t OFF_A    = 0;                       // 4194304
    const size_t OFF_H    = 4194304;                 // 4194304
    const size_t OFF_FFH  = 8388608;                 // 4096*4096 = 16777216
    const size_t OFF_FF   = 0;                       // reuse A (dead after H)
    const size_t OFF_LAM  = OFF_FFH + 16777216;      // 25165824

    float* qkv  = ws + OFF_QKV;
    float* q1   = ws + OFF_Q1;
    float* q2n  = ws + OFF_Q2;
    float* k1   = ws + OFF_K1;
    float* k2n  = ws + OFF_K2;
    float* arms = ws + OFF_ARMS;
    float* a    = ws + OFF_A;
    float* hbuf = ws + OFF_H;
    float* ffh  = ws + OFF_FFH;
    float* ff   = ws + OFF_FF;
    float* lam  = ws + OFF_LAM;

    // 1. lambda scalar
    lam_kernel<<<1, 64, 0, stream>>>(lq1, lk1, lq2, lk2, lam);

    // 2. qkv = x @ w_qkv   (4096 x 3072 x 1024)
    gemm_f32<0><<<dim3(3072 / 64, 4096 / 64), 256, 0, stream>>>(x, w_qkv, nullptr, qkv,
                                                                NT_, 3072, 1024);

    // 3. rope + split + q2/k2 rmsnorm
    rope_kernel<<<NT_, 256, 0, stream>>>(qkv, sigmas, lnq_w, lnq_b, q1, q2n, k1, k2n);

    // 4. dual causal attention + diff-combine + rmsnorm(128)
    attn_kernel<<<dim3(S_ / 32, H_, B_), 256, 0, stream>>>(q1, q2n, k1, k2n, qkv, lam,
                                                           ln_w, ln_b, arms);

    // 5. a = arms @ w_out  (4096 x 1024 x 1024)
    gemm_f32<0><<<dim3(1024 / 64, 4096 / 64), 256, 0, stream>>>(arms, w_out, nullptr, a,
                                                                NT_, 1024, 1024);

    // 6. h = LN(a + x)
    add_ln_kernel<<<NT_, 256, 0, stream>>>(a, x, ln1_w, ln1_b, hbuf, 1e-5f);

    // 7. ffh = silu(h @ w1 + b1)   (4096 x 4096 x 1024)
    gemm_f32<2><<<dim3(4096 / 64, 4096 / 64), 256, 0, stream>>>(hbuf, w1, b1, ffh,
                                                                NT_, 4096, 1024);

    // 8. ff = ffh @ w2 + b2   (4096 x 1024 x 4096)
    gemm_f32<1><<<dim3(1024 / 64, 4096 / 64), 256, 0, stream>>>(ffh, w2, b2, ff,
                                                                NT_, 1024, 4096);

    // 9. out = LN(ff + h)
    add_ln_kernel<<<NT_, 256, 0, stream>>>(ff, hbuf, ln2_w, ln2_b, (float*)d_out, 1e-5f);
}

// Round 2
// 564.014 us; speedup vs baseline: 4.8914x; 4.8914x over previous
//
#include <hip/hip_runtime.h>
#include <math.h>
#include <stdint.h>

#define B_ 2
#define S_ 2048
#define D_ 1024
#define H_ 8
#define NT_ (B_*S_)   // 4096 tokens

static constexpr float LAMBDA_INIT = 0.47071301834358415f;
static constexpr float ONE_MINUS_LI = 1.0f - 0.47071301834358415f;

typedef __attribute__((ext_vector_type(8))) short bf16x8;
typedef __attribute__((ext_vector_type(4))) float f32x4;
typedef __attribute__((ext_vector_type(8))) unsigned short us8;

__device__ __forceinline__ unsigned short f2bf(float x) {
    union { float f; unsigned int u; } v; v.f = x;
    unsigned int r = v.u + 0x7fffu + ((v.u >> 16) & 1u);
    return (unsigned short)(r >> 16);
}
__device__ __forceinline__ float bf2f(unsigned short b) {
    union { unsigned int u; float f; } v; v.u = ((unsigned int)b) << 16;
    return v.f;
}

#define GLD16(gp, lp) __builtin_amdgcn_global_load_lds( \
    (const __attribute__((address_space(1))) void*)(gp), \
    (__attribute__((address_space(3))) void*)(lp), 16, 0, 0)

// ---------------------------------------------------------------- lam scalar
__global__ void lam_kernel(const float* __restrict__ lq1, const float* __restrict__ lk1,
                           const float* __restrict__ lq2, const float* __restrict__ lk2,
                           float* __restrict__ lam_out) {
    int t = threadIdx.x;  // 64 threads
    float p1 = lq1[t] * lk1[t];
    float p2 = lq2[t] * lk2[t];
    for (int off = 32; off; off >>= 1) {
        p1 += __shfl_xor(p1, off);
        p2 += __shfl_xor(p2, off);
    }
    if (t == 0) lam_out[0] = expf(p1) - expf(p2) + LAMBDA_INIT;
}

// ---------------------------------------------------------------- f32 -> bf16
__global__ __launch_bounds__(256) void convert_bf16(const float* __restrict__ in,
                                                    short* __restrict__ out) {
    const size_t i = ((size_t)blockIdx.x * 256 + threadIdx.x) * 4;
    float4 v = *(const float4*)(in + i);
    ushort4 o = make_ushort4(f2bf(v.x), f2bf(v.y), f2bf(v.z), f2bf(v.w));
    *(ushort4*)(out + i) = o;
}

// --------------------------------------------- transpose + convert W[K][N] -> WT[N][K]
__global__ __launch_bounds__(256) void transpose_to_bf16(const float* __restrict__ W,
                                                         short* __restrict__ WT,
                                                         int K, int N) {
    __shared__ float tile[32][33];
    const int t = threadIdx.x;
    const int k0 = blockIdx.y * 32, n0 = blockIdx.x * 32;
    const int r = t >> 3, c0 = (t & 7) * 4;
    float4 v = *(const float4*)(W + (size_t)(k0 + r) * N + n0 + c0);
    tile[r][c0 + 0] = v.x; tile[r][c0 + 1] = v.y;
    tile[r][c0 + 2] = v.z; tile[r][c0 + 3] = v.w;
    __syncthreads();
    ushort4 o = make_ushort4(f2bf(tile[c0 + 0][r]), f2bf(tile[c0 + 1][r]),
                             f2bf(tile[c0 + 2][r]), f2bf(tile[c0 + 3][r]));
    *(ushort4*)(WT + (size_t)(n0 + r) * K + k0 + c0) = o;
}

// ---------------------------------------------------------------- bf16 MFMA GEMM
// C[M,N] = A[M,K] @ BT[N,K]^T.  128x128 tile, BK=32, 4 waves, 4x4 16x16 frags/wave.
// EPI: 0=none 1=bias 2=bias+silu.  OUTBF: 1 -> bf16 out, 0 -> f32 out.
template <int EPI, int OUTBF>
__global__ __launch_bounds__(256) void gemm_bt(const short* __restrict__ A,
                                               const short* __restrict__ BT,
                                               const float* __restrict__ bias,
                                               void* __restrict__ Cout,
                                               int M, int N, int K) {
    __shared__ short As[128 * 32];   // [row][k] 64B rows
    __shared__ short Bs[128 * 32];
    const int t = threadIdx.x;
    const int w = t >> 6, l = t & 63;
    const int lr = l & 15, lg = l >> 4;
    const int row0 = blockIdx.y * 128, col0 = blockIdx.x * 128;
    const int wr = (w >> 1) * 64, wc = (w & 1) * 64;

    f32x4 acc[4][4];
#pragma unroll
    for (int i = 0; i < 4; ++i)
#pragma unroll
        for (int j = 0; j < 4; ++j) acc[i][j] = (f32x4){0.f, 0.f, 0.f, 0.f};

    const short* Ag = A + (size_t)(row0 + w * 32 + (l >> 2)) * K + (l & 3) * 8;
    const short* Bg = BT + (size_t)(col0 + w * 32 + (l >> 2)) * K + (l & 3) * 8;

    for (int k0 = 0; k0 < K; k0 += 32) {
        __syncthreads();
#pragma unroll
        for (int j = 0; j < 2; ++j) {
            GLD16(Ag + k0 + (size_t)j * 16 * K, As + (w * 2 + j) * 512);
            GLD16(Bg + k0 + (size_t)j * 16 * K, Bs + (w * 2 + j) * 512);
        }
        __syncthreads();

        bf16x8 af[4], bfr[4];
#pragma unroll
        for (int i = 0; i < 4; ++i)
            af[i] = *(const bf16x8*)(As + (wr + i * 16 + lr) * 32 + lg * 8);
#pragma unroll
        for (int j = 0; j < 4; ++j)
            bfr[j] = *(const bf16x8*)(Bs + (wc + j * 16 + lr) * 32 + lg * 8);
#pragma unroll
        for (int i = 0; i < 4; ++i)
#pragma unroll
            for (int j = 0; j < 4; ++j)
                acc[i][j] = __builtin_amdgcn_mfma_f32_16x16x32_bf16(af[i], bfr[j], acc[i][j], 0, 0, 0);
    }

#pragma unroll
    for (int i = 0; i < 4; ++i) {
#pragma unroll
        for (int j = 0; j < 4; ++j) {
            const int col = col0 + wc + j * 16 + lr;
            float bcol = (EPI >= 1) ? bias[col] : 0.f;
#pragma unroll
            for (int r = 0; r < 4; ++r) {
                const int row = row0 + wr + i * 16 + lg * 4 + r;
                float v = acc[i][j][r];
                if (EPI >= 1) v += bcol;
                if (EPI == 2) v = v / (1.0f + expf(-v));
                if (OUTBF) ((short*)Cout)[(size_t)row * N + col] = (short)f2bf(v);
                else       ((float*)Cout)[(size_t)row * N + col] = v;
            }
        }
    }
}

// ------------------------------------------------- RoPE + split + q2/k2 RMSNorm (bf16 io)
__global__ __launch_bounds__(256) void rope_kernel(const short* __restrict__ qkv,
                                                   const float* __restrict__ sigmas,
                                                   const float* __restrict__ lnq_w,
                                                   const float* __restrict__ lnq_b,
                                                   short* __restrict__ q1, short* __restrict__ q2n,
                                                   short* __restrict__ k1, short* __restrict__ k2n) {
    const int tok = blockIdx.x;            // 0..4095
    const int b = tok >> 11, s = tok & 2047;
    const int t = threadIdx.x;
    const int hh = t >> 4;                 // 0..15 (head in 2H layout)
    const int d0 = (t & 15) * 4;

    const short* qrow = qkv + (size_t)tok * 3072 + hh * 64 + d0;
    ushort4 qv = *(const ushort4*)qrow;
    ushort4 kv = *(const ushort4*)(qrow + 1024);
    float q[4] = {bf2f(qv.x), bf2f(qv.y), bf2f(qv.z), bf2f(qv.w)};
    float k[4] = {bf2f(kv.x), bf2f(kv.y), bf2f(kv.z), bf2f(kv.w)};

    if (d0 < 32) {
#pragma unroll
        for (int pr = 0; pr < 2; ++pr) {
            const int i = d0 / 2 + pr;
            float freq = (float)s * powf(10000.0f, -(float)i / 16.0f);
            float sn, c;
            sincosf(freq, &sn, &c);
            float x0 = q[2 * pr], x1 = q[2 * pr + 1];
            q[2 * pr]     = x0 * c - x1 * sn;
            q[2 * pr + 1] = x1 * c + x0 * sn;
            x0 = k[2 * pr]; x1 = k[2 * pr + 1];
            k[2 * pr]     = x0 * c - x1 * sn;
            k[2 * pr + 1] = x1 * c + x0 * sn;
        }
    }

    const int h = hh >> 1, j = hh & 1;
    const size_t obase = ((size_t)(b * H_ + h) * S_ + s) * 64 + d0;
    if (j == 0) {
        *(ushort4*)&q1[obase] = make_ushort4(f2bf(q[0]), f2bf(q[1]), f2bf(q[2]), f2bf(q[3]));
        *(ushort4*)&k1[obase] = make_ushort4(f2bf(k[0]), f2bf(k[1]), f2bf(k[2]), f2bf(k[3]));
    } else {
        float ssq_q = 0.f, ssq_k = 0.f;
#pragma unroll
        for (int i = 0; i < 4; ++i) {
            const float sg = sigmas[b * 64 + d0 + i];
            q[i] += sg; k[i] += sg;
            ssq_q += q[i] * q[i];
            ssq_k += k[i] * k[i];
        }
        for (int off = 1; off < 16; off <<= 1) {
            ssq_q += __shfl_xor(ssq_q, off, 16);
            ssq_k += __shfl_xor(ssq_k, off, 16);
        }
        const float rq = rsqrtf(ssq_q / 64.0f + 1e-8f);
        const float rk = rsqrtf(ssq_k / 64.0f + 1e-8f);
        float oq[4], ok[4];
#pragma unroll
        for (int i = 0; i < 4; ++i) {
            const float w = lnq_w[d0 + i], bb = lnq_b[d0 + i];
            oq[i] = q[i] * rq * w + bb;
            ok[i] = k[i] * rk * w + bb;
        }
        *(ushort4*)&q2n[obase] = make_ushort4(f2bf(oq[0]), f2bf(oq[1]), f2bf(oq[2]), f2bf(oq[3]));
        *(ushort4*)&k2n[obase] = make_ushort4(f2bf(ok[0]), f2bf(ok[1]), f2bf(ok[2]), f2bf(ok[3]));
    }
}

// ------------------------------------------------- dual causal flash attention (MFMA)
// QBLK=64 (4 waves x 16 rows), KVBLK=64, D=64 per branch, E=128.
__device__ __forceinline__ void sm_update(f32x4 (&s)[4], float (&m)[4], float (&lsum)[4],
                                          f32x4 (&o)[8], short* __restrict__ Pw,
                                          const bool diag, const int qr0, const int k0,
                                          const int lr, const int lg) {
    float nm[4];
#pragma unroll
    for (int r = 0; r < 4; ++r) nm[r] = m[r];
#pragma unroll
    for (int ks = 0; ks < 4; ++ks) {
#pragma unroll
        for (int r = 0; r < 4; ++r) {
            float v = s[ks][r];
            if (diag && (k0 + ks * 16 + lr > qr0 + r)) v = -INFINITY;
            else v *= 0.125f;
            s[ks][r] = v;
            nm[r] = fmaxf(nm[r], v);
        }
    }
#pragma unroll
    for (int r = 0; r < 4; ++r) {
        nm[r] = fmaxf(nm[r], __shfl_xor(nm[r], 1));
        nm[r] = fmaxf(nm[r], __shfl_xor(nm[r], 2));
        nm[r] = fmaxf(nm[r], __shfl_xor(nm[r], 4));
        nm[r] = fmaxf(nm[r], __shfl_xor(nm[r], 8));
    }
    float al[4], rs[4];
#pragma unroll
    for (int r = 0; r < 4; ++r) { al[r] = __expf(m[r] - nm[r]); m[r] = nm[r]; rs[r] = 0.f; }
#pragma unroll
    for (int ks = 0; ks < 4; ++ks) {
#pragma unroll
        for (int r = 0; r < 4; ++r) {
            float p = __expf(s[ks][r] - nm[r]);
            rs[r] += p;
            Pw[(lg * 4 + r) * 72 + ks * 16 + lr] = (short)f2bf(p);
        }
    }
#pragma unroll
    for (int r = 0; r < 4; ++r) {
        rs[r] += __shfl_xor(rs[r], 1);
        rs[r] += __shfl_xor(rs[r], 2);
        rs[r] += __shfl_xor(rs[r], 4);
        rs[r] += __shfl_xor(rs[r], 8);
        lsum[r] = lsum[r] * al[r] + rs[r];
    }
#pragma unroll
    for (int es = 0; es < 8; ++es) {
#pragma unroll
        for (int r = 0; r < 4; ++r) o[es][r] *= al[r];
    }
}

__global__ __launch_bounds__(256) void attn_mfma(const short* __restrict__ q1g,
                                                 const short* __restrict__ q2g,
                                                 const short* __restrict__ k1g,
                                                 const short* __restrict__ k2g,
                                                 const short* __restrict__ qkv_bf,
                                                 const float* __restrict__ lamp,
                                                 const float* __restrict__ ln_w,
                                                 const float* __restrict__ ln_b,
                                                 short* __restrict__ arms) {
    __shared__ short Ks1[64 * 72];
    __shared__ short Ks2[64 * 72];
    __shared__ short Vt[128 * 72];     // [e][k] transposed
    __shared__ short Ps1[4][16 * 72];
    __shared__ short Ps2[4][16 * 72];

    const int qt = blockIdx.x, h = blockIdx.y, b = blockIdx.z;
    const int q0 = qt * 64;
    const int t = threadIdx.x, w = t >> 6, l = t & 63;
    const int lr = l & 15, lg = l >> 4;
    const float lam = lamp[0];

    const size_t qkbase = ((size_t)(b * H_ + h) * S_) * 64;

    // Q fragments (held in registers)
    bf16x8 qa1[2], qa2[2];
    {
        const size_t rbase = qkbase + (size_t)(q0 + w * 16 + lr) * 64;
#pragma unroll
        for (int dh = 0; dh < 2; ++dh) {
            qa1[dh] = *(const bf16x8*)(q1g + rbase + dh * 32 + lg * 8);
            qa2[dh] = *(const bf16x8*)(q2g + rbase + dh * 32 + lg * 8);
        }
    }

    float m1[4], m2[4], l1[4], l2[4];
#pragma unroll
    for (int r = 0; r < 4; ++r) { m1[r] = -INFINITY; m2[r] = -INFINITY; l1[r] = 0.f; l2[r] = 0.f; }
    f32x4 o1[8], o2[8];
#pragma unroll
    for (int es = 0; es < 8; ++es) { o1[es] = (f32x4){0.f,0.f,0.f,0.f}; o2[es] = (f32x4){0.f,0.f,0.f,0.f}; }

    short* Pw1 = &Ps1[w][0];
    short* Pw2 = &Ps2[w][0];
    const int qr0 = q0 + w * 16 + lg * 4;

    for (int kt = 0; kt <= qt; ++kt) {
        const int k0 = kt * 64;
        __syncthreads();
        // stage K1, K2 tiles [64][72]
        {
            const int row = t >> 2, c = (t & 3) * 16;
            const size_t g = qkbase + (size_t)(k0 + row) * 64 + c;
            *(uint4*)(Ks1 + row * 72 + c)     = *(const uint4*)(k1g + g);
            *(uint4*)(Ks1 + row * 72 + c + 8) = *(const uint4*)(k1g + g + 8);
            *(uint4*)(Ks2 + row * 72 + c)     = *(const uint4*)(k2g + g);
            *(uint4*)(Ks2 + row * 72 + c + 8) = *(const uint4*)(k2g + g + 8);
        }
        // stage V transposed: Vt[e][k]
        {
            const int k = t >> 2, e0 = (t & 3) * 32;
            const short* vp = qkv_bf + (size_t)(b * S_ + k0 + k) * 3072 + 2048 + h * 128 + e0;
#pragma unroll
            for (int j = 0; j < 32; j += 8) {
                us8 vv = *(const us8*)(vp + j);
#pragma unroll
                for (int i = 0; i < 8; ++i) Vt[(e0 + j + i) * 72 + k] = (short)vv[i];
            }
        }
        __syncthreads();

        const bool diag = (kt == qt);

        // QK^T both branches
        f32x4 s1[4], s2[4];
#pragma unroll
        for (int ks = 0; ks < 4; ++ks) { s1[ks] = (f32x4){0.f,0.f,0.f,0.f}; s2[ks] = (f32x4){0.f,0.f,0.f,0.f}; }
#pragma unroll
        for (int ks = 0; ks < 4; ++ks) {
#pragma unroll
            for (int dh = 0; dh < 2; ++dh) {
                bf16x8 kb1 = *(const bf16x8*)((const char*)Ks1 + (ks * 16 + lr) * 144 + dh * 64 + lg * 16);
                bf16x8 kb2 = *(const bf16x8*)((const char*)Ks2 + (ks * 16 + lr) * 144 + dh * 64 + lg * 16);
                s1[ks] = __builtin_amdgcn_mfma_f32_16x16x32_bf16(qa1[dh], kb1, s1[ks], 0, 0, 0);
                s2[ks] = __builtin_amdgcn_mfma_f32_16x16x32_bf16(qa2[dh], kb2, s2[ks], 0, 0, 0);
            }
        }

        sm_update(s1, m1, l1, o1, Pw1, diag, qr0, k0, lr, lg);
        sm_update(s2, m2, l2, o2, Pw2, diag, qr0, k0, lr, lg);

        // PV both branches
#pragma unroll
        for (int kb = 0; kb < 2; ++kb) {
            bf16x8 p1f = *(const bf16x8*)((const char*)Pw1 + lr * 144 + kb * 64 + lg * 16);
            bf16x8 p2f = *(const bf16x8*)((const char*)Pw2 + lr * 144 + kb * 64 + lg * 16);
#pragma unroll
            for (int es = 0; es < 8; ++es) {
                bf16x8 vf = *(const bf16x8*)((const char*)Vt + (es * 16 + lr) * 144 + kb * 64 + lg * 16);
                o1[es] = __builtin_amdgcn_mfma_f32_16x16x32_bf16(p1f, vf, o1[es], 0, 0, 0);
                o2[es] = __builtin_amdgcn_mfma_f32_16x16x32_bf16(p2f, vf, o2[es], 0, 0, 0);
            }
        }
    }

    // epilogue: combine, RMSNorm(128), scale, store bf16
    float inv1[4], inv2[4];
#pragma unroll
    for (int r = 0; r < 4; ++r) { inv1[r] = 1.0f / l1[r]; inv2[r] = 1.0f / l2[r]; }
    float comb[8][4];
    float ssq[4] = {0.f, 0.f, 0.f, 0.f};
#pragma unroll
    for (int es = 0; es < 8; ++es) {
#pragma unroll
        for (int r = 0; r < 4; ++r) {
            const float c = o1[es][r] * inv1[r] - lam * (o2[es][r] * inv2[r]);
            comb[es][r] = c;
            ssq[r] += c * c;
        }
    }
#pragma unroll
    for (int r = 0; r < 4; ++r) {
        ssq[r] += __shfl_xor(ssq[r], 1);
        ssq[r] += __shfl_xor(ssq[r], 2);
        ssq[r] += __shfl_xor(ssq[r], 4);
        ssq[r] += __shfl_xor(ssq[r], 8);
    }
    float rms[4];
#pragma unroll
    for (int r = 0; r < 4; ++r) rms[r] = rsqrtf(ssq[r] / 128.0f + 1e-8f);

    float lnw[8], lnb[8];
#pragma unroll
    for (int es = 0; es < 8; ++es) { lnw[es] = ln_w[es * 16 + lr]; lnb[es] = ln_b[es * 16 + lr]; }

#pragma unroll
    for (int es = 0; es < 8; ++es) {
#pragma unroll
        for (int r = 0; r < 4; ++r) {
            const int tok = b * S_ + q0 + w * 16 + lg * 4 + r;
            const int col = h * 128 + es * 16 + lr;
            const float v = (comb[es][r] * rms[r] * lnw[es] + lnb[es]) * ONE_MINUS_LI;
            arms[(size_t)tok * 1024 + col] = (short)f2bf(v);
        }
    }
}

// ---------------------------------------------------------------- add + LayerNorm
template <int WB>
__global__ __launch_bounds__(256) void add_ln_kernel(const float* __restrict__ X,
                                                     const float* __restrict__ Y,
                                                     const float* __restrict__ w,
                                                     const float* __restrict__ bvec,
                                                     float* __restrict__ out,
                                                     short* __restrict__ out_bf,
                                                     float eps) {
    const int row = blockIdx.x;
    const int t = threadIdx.x;
    __shared__ float red[4];

    float4 xv = *(const float4*)&X[(size_t)row * 1024 + t * 4];
    float4 yv = *(const float4*)&Y[(size_t)row * 1024 + t * 4];
    float v[4] = {xv.x + yv.x, xv.y + yv.y, xv.z + yv.z, xv.w + yv.w};

    float s = v[0] + v[1] + v[2] + v[3];
    for (int off = 1; off < 64; off <<= 1) s += __shfl_xor(s, off);
    if ((t & 63) == 0) red[t >> 6] = s;
    __syncthreads();
    const float mean = (red[0] + red[1] + red[2] + red[3]) * (1.0f / 1024.0f);

    float sq = 0.f;
#pragma unroll
    for (int i = 0; i < 4; ++i) { const float d = v[i] - mean; sq += d * d; }
    __syncthreads();
    for (int off = 1; off < 64; off <<= 1) sq += __shfl_xor(sq, off);
    if ((t & 63) == 0) red[t >> 6] = sq;
    __syncthreads();
    const float var = (red[0] + red[1] + red[2] + red[3]) * (1.0f / 1024.0f);
    const float rstd = rsqrtf(var + eps);

    float o[4];
#pragma unroll
    for (int i = 0; i < 4; ++i)
        o[i] = (v[i] - mean) * rstd * w[t * 4 + i] + bvec[t * 4 + i];
    *(float4*)&out[(size_t)row * 1024 + t * 4] = make_float4(o[0], o[1], o[2], o[3]);
    if (WB) {
        *(ushort4*)&out_bf[(size_t)row * 1024 + t * 4] =
            make_ushort4(f2bf(o[0]), f2bf(o[1]), f2bf(o[2]), f2bf(o[3]));
    }
}

// ---------------------------------------------------------------- launch
extern "C" void kernel_launch(void* const* d_in, const int* in_sizes, int n_in,
                              void* d_out, int out_size, void* d_ws, size_t ws_size,
                              hipStream_t stream) {
    const float* x      = (const float*)d_in[0];
    const float* sigmas = (const float*)d_in[1];
    const float* w_qkv  = (const float*)d_in[2];
    const float* w_out  = (const float*)d_in[3];
    const float* lq1    = (const float*)d_in[4];
    const float* lk1    = (const float*)d_in[5];
    const float* lq2    = (const float*)d_in[6];
    const float* lk2    = (const float*)d_in[7];
    const float* ln_w   = (const float*)d_in[8];
    const float* ln_b   = (const float*)d_in[9];
    const float* lnq_w  = (const float*)d_in[10];
    const float* lnq_b  = (const float*)d_in[11];
    const float* ln1_w  = (const float*)d_in[12];
    const float* ln1_b  = (const float*)d_in[13];
    const float* ln2_w  = (const float*)d_in[14];
    const float* ln2_b  = (const float*)d_in[15];
    const float* w1     = (const float*)d_in[16];
    const float* b1     = (const float*)d_in[17];
    const float* w2     = (const float*)d_in[18];
    const float* b2     = (const float*)d_in[19];

    char* ws = (char*)d_ws;
    // byte offsets
    short* x_bf    = (short*)(ws + 0);            //  8,388,608
    short* w_qkvT  = (short*)(ws + 8388608);      //  6,291,456
    short* w_outT  = (short*)(ws + 14680064);     //  2,097,152
    short* w1T     = (short*)(ws + 16777216);     //  8,388,608
    short* w2T     = (short*)(ws + 25165824);     //  8,388,608
    short* qkv_bf  = (short*)(ws + 33554432);     // 25,165,824
    short* q1      = (short*)(ws + 58720256);     //  4,194,304
    short* q2n     = (short*)(ws + 62914560);
    short* k1      = (short*)(ws + 67108864);
    short* k2n     = (short*)(ws + 71303168);
    short* arms    = (short*)(ws + 75497472);     //  8,388,608
    float* a_f32   = (float*)(ws + 83886080);     // 16,777,216
    float* h_f32   = (float*)(ws + 33554432);     // reuse qkv_bf (dead after attn)
    short* h_bf    = (short*)(ws + 50331648);
    short* ffh     = (short*)(ws + 58720256);     // reuse q/k + arms (33,554,432)
    float* ff      = (float*)(ws + 0);            // reuse x_bf + weights (16,777,216)
    float* lam     = (float*)(ws + 100663296);

    // 1. lambda
    lam_kernel<<<1, 64, 0, stream>>>(lq1, lk1, lq2, lk2, lam);

    // 2. conversions
    convert_bf16<<<4096, 256, 0, stream>>>(x, x_bf);
    transpose_to_bf16<<<dim3(3072 / 32, 1024 / 32), 256, 0, stream>>>(w_qkv, w_qkvT, 1024, 3072);
    transpose_to_bf16<<<dim3(1024 / 32, 1024 / 32), 256, 0, stream>>>(w_out, w_outT, 1024, 1024);
    transpose_to_bf16<<<dim3(4096 / 32, 1024 / 32), 256, 0, stream>>>(w1, w1T, 1024, 4096);
    transpose_to_bf16<<<dim3(1024 / 32, 4096 / 32), 256, 0, stream>>>(w2, w2T, 4096, 1024);

    // 3. qkv = x @ w_qkv  -> bf16
    gemm_bt<0, 1><<<dim3(3072 / 128, 4096 / 128), 256, 0, stream>>>(x_bf, w_qkvT, nullptr,
                                                                    qkv_bf, NT_, 3072, 1024);

    // 4. rope + split + q2/k2 rmsnorm
    rope_kernel<<<NT_, 256, 0, stream>>>(qkv_bf, sigmas, lnq_w, lnq_b, q1, q2n, k1, k2n);

    // 5. dual attention + combine + rmsnorm(128)
    attn_mfma<<<dim3(S_ / 64, H_, B_), 256, 0, stream>>>(q1, q2n, k1, k2n, qkv_bf, lam,
                                                         ln_w, ln_b, arms);

    // 6. a = arms @ w_out -> f32
    gemm_bt<0, 0><<<dim3(1024 / 128, 4096 / 128), 256, 0, stream>>>(arms, w_outT, nullptr,
                                                                    a_f32, NT_, 1024, 1024);

    // 7. h = LN(a + x) -> f32 + bf16
    add_ln_kernel<1><<<NT_, 256, 0, stream>>>(a_f32, x, ln1_w, ln1_b, h_f32, h_bf, 1e-5f);

    // 8. ffh = silu(h @ w1 + b1) -> bf16
    gemm_bt<2, 1><<<dim3(4096 / 128, 4096 / 128), 256, 0, stream>>>(h_bf, w1T, b1,
                                                                    ffh, NT_, 4096, 1024);

    // 9. ff = ffh @ w2 + b2 -> f32
    gemm_bt<1, 0><<<dim3(1024 / 128, 4096 / 128), 256, 0, stream>>>(ffh, w2T, b2,
                                                                    ff, NT_, 1024, 4096);

    // 10. out = LN(ff + h)
    add_ln_kernel<0><<<NT_, 256, 0, stream>>>(ff, h_f32, ln2_w, ln2_b, (float*)d_out,
                                              nullptr, 1e-5f);
}